// Round 1
// baseline (207.632 us; speedup 1.0000x reference)
//
#include <hip/hip_runtime.h>
#include <math.h>

#define DEV __device__ __forceinline__

DEV float rcp_fast(float x) { return __builtin_amdgcn_rcpf(x); }
DEV float rsq_fast(float x) { return __builtin_amdgcn_rsqf(x); }

// packed upper-triangle index for NxN symmetric, requires i<=j
__host__ __device__ constexpr int TI(int n, int i, int j) {
  return n * i - (i * (i - 1)) / 2 + (j - i);
}

template <int N>
DEV float& sym_at(float (&a)[N * (N + 1) / 2], int i, int j) {
  return (i <= j) ? a[TI(N, i, j)] : a[TI(N, j, i)];
}

// --- branchless rotation params + exact diagonal-block update -------------
template <int N>
DEV void pivot_params(float (&a)[N * (N + 1) / 2], int p, int q,
                      float& c_out, float& s_out) {
  float apq = a[TI(N, p, q)];
  float app = a[TI(N, p, p)];
  float aqq = a[TI(N, q, q)];
  float h = aqq - app;
  float tw = apq + apq;
  float den = fabsf(h) + sqrtf(fmaf(h, h, tw * tw)) + 1e-37f;
  float t = tw * rcp_fast(den);
  t = (h < 0.0f) ? -t : t;
  float c = rsq_fast(fmaf(t, t, 1.0f));
  float s = t * c;
  c_out = c;
  s_out = s;
  a[TI(N, p, p)] = fmaf(-t, apq, app);
  a[TI(N, q, q)] = fmaf( t, apq, aqq);
  a[TI(N, p, q)] = 0.0f;
}

template <int N>
DEV void cross_update(float (&a)[N * (N + 1) / 2], int pa, int qa, int pb,
                      int qb, float ca, float sa, float cb, float sb) {
  float w = sym_at<N>(a, pa, pb), x = sym_at<N>(a, pa, qb);
  float y = sym_at<N>(a, qa, pb), z = sym_at<N>(a, qa, qb);
  float w1 = fmaf(ca, w, -sa * y), x1 = fmaf(ca, x, -sa * z);
  float y1 = fmaf(sa, w,  ca * y), z1 = fmaf(sa, x,  ca * z);
  sym_at<N>(a, pa, pb) = fmaf(cb, w1, -sb * x1);
  sym_at<N>(a, pa, qb) = fmaf(sb, w1,  cb * x1);
  sym_at<N>(a, qa, pb) = fmaf(cb, y1, -sb * z1);
  sym_at<N>(a, qa, qb) = fmaf(sb, y1,  cb * z1);
}

// Fused Jacobi: 8x8 parallel-ordering rounds (SW8*7) with the two
// independent 4x4 problems' rounds (SW4*3) interleaved every other 8x8
// round. Identical operations and per-problem ordering as the previous
// sequential pjacobi8<3> + pjacobi4x2<3>; the interleave only widens the
// independent-instruction pool so the single-wave-per-SIMD phi kernel can
// hide the sqrt/rcp/rsq dependent-chain latency with ILP.
template <int SW8, int SW4>
DEV void jacobi_fused(float (&W)[36], float (&L)[10], float (&R)[10]) {
  constexpr int P8[7][4][2] = {
      {{0, 7}, {1, 6}, {2, 5}, {3, 4}}, {{0, 1}, {2, 7}, {3, 6}, {4, 5}},
      {{0, 2}, {1, 3}, {4, 7}, {5, 6}}, {{0, 3}, {2, 4}, {1, 5}, {6, 7}},
      {{0, 4}, {3, 5}, {2, 6}, {1, 7}}, {{0, 5}, {4, 6}, {3, 7}, {1, 2}},
      {{0, 6}, {5, 7}, {1, 4}, {2, 3}}};
  constexpr int P4[3][2][2] = {
      {{0, 3}, {1, 2}}, {{0, 1}, {2, 3}}, {{0, 2}, {1, 3}}};
#pragma unroll
  for (int rr = 0; rr < SW8 * 7; ++rr) {
    const int r = rr % 7;
    const bool do4 = ((rr & 1) == 0) && ((rr >> 1) < SW4 * 3);
    const int q = (rr >> 1) % 3;  // 4x4 round index when do4

    float cc[4], ss[4];
#pragma unroll
    for (int u = 0; u < 4; ++u)
      pivot_params<8>(W, P8[r][u][0], P8[r][u][1], cc[u], ss[u]);

    float ca0, sa0, ca1, sa1, cb0, sb0, cb1, sb1;
    if (do4) {
      pivot_params<4>(L, P4[q][0][0], P4[q][0][1], ca0, sa0);
      pivot_params<4>(R, P4[q][0][0], P4[q][0][1], cb0, sb0);
      pivot_params<4>(L, P4[q][1][0], P4[q][1][1], ca1, sa1);
      pivot_params<4>(R, P4[q][1][0], P4[q][1][1], cb1, sb1);
    }

#pragma unroll
    for (int u = 0; u < 4; ++u) {
#pragma unroll
      for (int v = u + 1; v < 4; ++v) {
        cross_update<8>(W, P8[r][u][0], P8[r][u][1], P8[r][v][0], P8[r][v][1],
                        cc[u], ss[u], cc[v], ss[v]);
      }
    }

    if (do4) {
      cross_update<4>(L, P4[q][0][0], P4[q][0][1], P4[q][1][0], P4[q][1][1],
                      ca0, sa0, ca1, sa1);
      cross_update<4>(R, P4[q][0][0], P4[q][0][1], P4[q][1][0], P4[q][1][1],
                      cb0, sb0, cb1, sb1);
    }
  }
}

// entropy mirroring reference EPS placement
template <int N>
DEV float entropy_of(const float (&a)[N * (N + 1) / 2]) {
  float lam[N];
  float sum = 0.0f;
#pragma unroll
  for (int i = 0; i < N; ++i) {
    float l = fmaxf(a[TI(N, i, i)], 0.0f) + 1e-10f;
    lam[i] = l;
    sum += l;
  }
  float inv = 1.0f / sum;
  float H = 0.0f;
#pragma unroll
  for (int i = 0; i < N; ++i) {
    float p = lam[i] * inv;
    H = fmaf(p, __logf(p + 1e-10f), H);
  }
  return -H;
}

// --- cross-lane reduction with distribution -------------------------------
DEV float reduce_dist_64(float (&cur)[64], int lane) {
#pragma unroll
  for (int d = 0; d < 6; ++d) {
    const int dist = 1 << d;
    const int up = (lane >> d) & 1;
#pragma unroll
    for (int m = 0; m < (64 >> (d + 1)); ++m) {
      float snd = up ? cur[2 * m]     : cur[2 * m + 1];
      float kp  = up ? cur[2 * m + 1] : cur[2 * m];
      float r = __shfl_xor(snd, dist, 64);
      cur[m] = kp + r;
    }
  }
  return cur[0];
}

DEV float reduce_dist_32(float (&cur)[32], int lane) {
#pragma unroll
  for (int d = 0; d < 5; ++d) {
    const int dist = 1 << d;
    const int up = (lane >> d) & 1;
#pragma unroll
    for (int m = 0; m < (32 >> (d + 1)); ++m) {
      float snd = up ? cur[2 * m]     : cur[2 * m + 1];
      float kp  = up ? cur[2 * m + 1] : cur[2 * m];
      float r = __shfl_xor(snd, dist, 64);
      cur[m] = kp + r;
    }
  }
  float v = cur[0];
  v += __shfl_xor(v, 32, 64);
  return v;
}

// --- Phase 1: correlation matrices (one wave per batch) -------------------
// Layout: cmat[b * 96 + e]  (row per batch -> fully coalesced stores)
//   e in [0,64):  C_whole[i][j], e = i*8+j
//   e in [64,80): C_left;  e in [80,96): C_right
__global__ __launch_bounds__(64) void corr_kernel(
    const float* __restrict__ sites, float* __restrict__ cmat) {
  const int b = blockIdx.x;
  const int lane = threadIdx.x;
  const float4* base = reinterpret_cast<const float4*>(sites) + (size_t)b * 1024;

  float4 v[16];
#pragma unroll
  for (int s = 0; s < 16; ++s) v[s] = base[s * 64 + lane];

  float aw[64];
#pragma unroll
  for (int i = 0; i < 8; ++i) {
#pragma unroll
    for (int j = 0; j < 8; ++j) {
      float4 a = v[i], c = v[8 + j];
      aw[i * 8 + j] =
          fmaf(a.x, c.x, fmaf(a.y, c.y, fmaf(a.z, c.z, a.w * c.w)));
    }
  }
  float cw = reduce_dist_64(aw, lane);

  float alr[32];
#pragma unroll
  for (int i = 0; i < 4; ++i) {
#pragma unroll
    for (int j = 0; j < 4; ++j) {
      float4 a = v[i], c = v[4 + j];
      alr[i * 4 + j] =
          fmaf(a.x, c.x, fmaf(a.y, c.y, fmaf(a.z, c.z, a.w * c.w)));
      float4 a2 = v[8 + i], c2 = v[12 + j];
      alr[16 + i * 4 + j] =
          fmaf(a2.x, c2.x, fmaf(a2.y, c2.y, fmaf(a2.z, c2.z, a2.w * c2.w)));
    }
  }
  float clr = reduce_dist_32(alr, lane);

  float* row = cmat + (size_t)b * 96;
  row[lane] = cw;                        // e = 0..63, contiguous 256B
  if (lane < 32) row[64 + lane] = clr;   // e = 64..95, contiguous 128B
}

// --- Phase 2: eigenvalues + entropies -------------------------------------
// Block = 64 threads = 64 batches, one thread per batch. NOTE: keep
// __launch_bounds__(64) with no min-wave arg — lets the compiler take ~256
// VGPRs for the ~150-value working set. Capping VGPRs (as the fused R5
// kernel did at 108) causes scratch spills and a 10x slowdown.
__global__ __launch_bounds__(64) void phi_kernel(
    const float* __restrict__ cmat, float* __restrict__ out) {
  __shared__ float4 lds[64 * 25];
  const int t = threadIdx.x;
  const int b0 = blockIdx.x * 64;

  const float4* src = reinterpret_cast<const float4*>(cmat) + (size_t)b0 * 24;
#pragma unroll
  for (int r = 0; r < 24; ++r) {
    int q = r * 64 + t;
    float4 val = src[q];
    int bl = q / 24;
    int e4 = q - bl * 24;
    lds[bl * 25 + e4] = val;
  }
  __syncthreads();

  const float4* myrow = &lds[t * 25];
  float Cw[64], Cl[16], Cr[16];
#pragma unroll
  for (int j = 0; j < 16; ++j) {
    float4 f = myrow[j];
    Cw[4 * j] = f.x; Cw[4 * j + 1] = f.y; Cw[4 * j + 2] = f.z; Cw[4 * j + 3] = f.w;
  }
#pragma unroll
  for (int j = 0; j < 4; ++j) {
    float4 f = myrow[16 + j];
    Cl[4 * j] = f.x; Cl[4 * j + 1] = f.y; Cl[4 * j + 2] = f.z; Cl[4 * j + 3] = f.w;
    float4 g = myrow[20 + j];
    Cr[4 * j] = g.x; Cr[4 * j + 1] = g.y; Cr[4 * j + 2] = g.z; Cr[4 * j + 3] = g.w;
  }

  float Mw[36];
#pragma unroll
  for (int i = 0; i < 8; ++i) {
#pragma unroll
    for (int j = i; j < 8; ++j) {
      float acc = 0.0f;
#pragma unroll
      for (int k = 0; k < 8; ++k) acc = fmaf(Cw[i * 8 + k], Cw[j * 8 + k], acc);
      Mw[TI(8, i, j)] = acc;
    }
  }
  float Ml[10], Mr[10];
#pragma unroll
  for (int i = 0; i < 4; ++i) {
#pragma unroll
    for (int j = i; j < 4; ++j) {
      float accl = 0.0f, accr = 0.0f;
#pragma unroll
      for (int k = 0; k < 4; ++k) {
        accl = fmaf(Cl[i * 4 + k], Cl[j * 4 + k], accl);
        accr = fmaf(Cr[i * 4 + k], Cr[j * 4 + k], accr);
      }
      Ml[TI(4, i, j)] = accl;
      Mr[TI(4, i, j)] = accr;
    }
  }

  // 3 sweeps each, interleaved for ILP (numerically identical to the
  // previous sequential pjacobi8<3> + pjacobi4x2<3>; absmax 4.9e-3 vs 2e-2).
  jacobi_fused<3, 3>(Mw, Ml, Mr);

  float Sw = entropy_of<8>(Mw);
  float Sl = entropy_of<4>(Ml);
  float Sr = entropy_of<4>(Mr);

  out[b0 + t] = fmaxf(Sw - Sl - Sr, 0.0f);
}

extern "C" void kernel_launch(void* const* d_in, const int* in_sizes, int n_in,
                              void* d_out, int out_size, void* d_ws, size_t ws_size,
                              hipStream_t stream) {
  const float* sites = (const float*)d_in[0];   // [8192, 16, 256] f32
  float* out = (float*)d_out;                   // [8192] f32
  float* cmat = (float*)d_ws;                   // 8192*96*4 = 3 MiB used

  corr_kernel<<<8192, 64, 0, stream>>>(sites, cmat);
  phi_kernel<<<128, 64, 0, stream>>>(cmat, out);
}

// Round 3
// 205.936 us; speedup vs baseline: 1.0082x; 1.0082x over previous
//
#include <hip/hip_runtime.h>
#include <math.h>

#define DEV __device__ __forceinline__

DEV float rcp_fast(float x) { return __builtin_amdgcn_rcpf(x); }
DEV float rsq_fast(float x) { return __builtin_amdgcn_rsqf(x); }

// ===========================================================================
// Phase 2 redesign: lane-parallel Jacobi, 4 lanes per batch.
//
// Key insight: the parallel-ordering table P8 used by the previous per-thread
// Jacobi IS the circle (round-robin tournament) ordering: positions
// T0..T3 / B0..B3, pairs are columns (Tv,Bv), and between rounds the
// occupants rotate along the fixed 7-cycle T1->B0->B1->B2->B3->T3->T2->T1
// (T0 fixed). Storing rows in POSITION order makes every round identical and
// every register index compile-time:
//   - lane u of a 4-lane group owns the rows at positions T_u and B_u
//   - each row stores its 8 elements by position-slot: slot 2v = col at T_v,
//     slot 2v+1 = col at B_v
//   - pivot for lane u reads slots (2u,2u+1)  (small cndmask trees)
//   - column rotations touch slots (2v,2v+1), v compile-time
//   - migration = fixed lane shuffle + fixed slot permutation
//     SRC8 = {0,2,4,1,6,3,7,5}   (verified against P8 rounds 0..3)
// The two 4x4 problems (L on lanes 0-1, R on lanes 2-3) use the same scheme
// with SRC4 = {0,2,3,1} (verified against P4), interleaved into even W-rounds
// for ILP. All lanes execute one instruction stream -> no divergence.
// Same rotation formulas / EPS placement as the validated per-thread version.
// ===========================================================================

DEV void jac_pivot(float app, float apq, float aqq, float& c, float& s) {
  float h = aqq - app;
  float tw = apq + apq;
  float den = fabsf(h) + sqrtf(fmaf(h, h, tw * tw)) + 1e-37f;
  float t = tw * rcp_fast(den);
  t = (h < 0.0f) ? -t : t;
  c = rsq_fast(fmaf(t, t, 1.0f));
  s = t * c;
}

// one W round: pivot on my pair, row rotation (left), column rotations (right)
DEV void w_round(float (&rT)[8], float (&rB)[8], int u, int gbase) {
  const bool q0 = (u & 1) != 0, q1 = (u & 2) != 0;
  // extract a[p][p], a[p][q], a[q][q] at slots 2u, 2u+1 (cndmask trees)
  float appA = q0 ? rT[2] : rT[0], appB = q0 ? rT[6] : rT[4];
  float app = q1 ? appB : appA;
  float apqA = q0 ? rT[3] : rT[1], apqB = q0 ? rT[7] : rT[5];
  float apq = q1 ? apqB : apqA;
  float aqqA = q0 ? rB[3] : rB[1], aqqB = q0 ? rB[7] : rB[5];
  float aqq = q1 ? aqqB : aqqA;

  float c, s;
  jac_pivot(app, apq, aqq, c, s);

  // row rotation: rows (p,q) are my (rT,rB); disjoint pairs -> local only
#pragma unroll
  for (int j = 0; j < 8; ++j) {
    float x = rT[j], y = rB[j];
    rT[j] = fmaf(c, x, -s * y);
    rB[j] = fmaf(s, x, c * y);
  }
  // column rotations: all 4 pairs' (c,s), columns at compile-time slots
#pragma unroll
  for (int v = 0; v < 4; ++v) {
    float cv = __shfl(c, gbase + v, 64);
    float sv = __shfl(s, gbase + v, 64);
    float x = rT[2 * v], y = rT[2 * v + 1];
    rT[2 * v] = fmaf(cv, x, -sv * y);
    rT[2 * v + 1] = fmaf(sv, x, cv * y);
    float x2 = rB[2 * v], y2 = rB[2 * v + 1];
    rB[2 * v] = fmaf(cv, x2, -sv * y2);
    rB[2 * v + 1] = fmaf(sv, x2, cv * y2);
  }
}

// circle-method migration: rows move between lanes, slots permute (both fixed)
DEV void w_migrate(float (&rT)[8], float (&rB)[8], int u, int gbase) {
  constexpr int SRC[8] = {0, 2, 4, 1, 6, 3, 7, 5};
  const int upLane = gbase + ((u + 1) & 3);
  const int dnLane = gbase + ((u + 3) & 3);
  const bool u0 = (u == 0), u3 = (u == 3);
  float nT[8], nB[8];
#pragma unroll
  for (int sdst = 0; sdst < 8; ++sdst) {
    const int j = SRC[sdst];
    float tsh = __shfl(rT[j], upLane, 64);  // lane u+1's T row
    float bsh = __shfl(rB[j], dnLane, 64);  // lane u-1's B row
    // newT: u0 keeps own T; u3 takes own B; else lane u+1's T
    nT[sdst] = u0 ? rT[j] : (u3 ? rB[j] : tsh);
    // newB: u0 takes lane1's T; else lane u-1's B
    nB[sdst] = u0 ? tsh : bsh;
  }
#pragma unroll
  for (int sdst = 0; sdst < 8; ++sdst) { rT[sdst] = nT[sdst]; rB[sdst] = nB[sdst]; }
}

// 4x4 analog on 2-lane groups (L: lanes 0-1, R: lanes 2-3 of each group)
DEV void h_round(float (&rT)[4], float (&rB)[4], int w, int base2) {
  float app = w ? rT[2] : rT[0];
  float apq = w ? rT[3] : rT[1];
  float aqq = w ? rB[3] : rB[1];
  float c, s;
  jac_pivot(app, apq, aqq, c, s);
#pragma unroll
  for (int j = 0; j < 4; ++j) {
    float x = rT[j], y = rB[j];
    rT[j] = fmaf(c, x, -s * y);
    rB[j] = fmaf(s, x, c * y);
  }
#pragma unroll
  for (int v = 0; v < 2; ++v) {
    float cv = __shfl(c, base2 + v, 64);
    float sv = __shfl(s, base2 + v, 64);
    float x = rT[2 * v], y = rT[2 * v + 1];
    rT[2 * v] = fmaf(cv, x, -sv * y);
    rT[2 * v + 1] = fmaf(sv, x, cv * y);
    float x2 = rB[2 * v], y2 = rB[2 * v + 1];
    rB[2 * v] = fmaf(cv, x2, -sv * y2);
    rB[2 * v + 1] = fmaf(sv, x2, cv * y2);
  }
}

DEV void h_migrate(float (&rT)[4], float (&rB)[4], int w) {
  constexpr int SRC[4] = {0, 2, 3, 1};
  const bool w0 = (w == 0);
  float nT[4], nB[4];
#pragma unroll
  for (int sdst = 0; sdst < 4; ++sdst) {
    const int j = SRC[sdst];
    float snd = w0 ? rB[j] : rT[j];       // donor side: lane0 sends B, lane1 sends T
    float got = __shfl_xor(snd, 1, 64);
    nT[sdst] = w0 ? rT[j] : rB[j];        // lane0 keeps T; lane1's new T = own B
    nB[sdst] = got;                       // lane0: partner's T; lane1: partner's B
  }
#pragma unroll
  for (int sdst = 0; sdst < 4; ++sdst) { rT[sdst] = nT[sdst]; rB[sdst] = nB[sdst]; }
}

DEV float dot8(const float (&A)[8], float4 c0, float4 c1) {
  float acc = A[0] * c0.x;
  acc = fmaf(A[1], c0.y, acc);
  acc = fmaf(A[2], c0.z, acc);
  acc = fmaf(A[3], c0.w, acc);
  acc = fmaf(A[4], c1.x, acc);
  acc = fmaf(A[5], c1.y, acc);
  acc = fmaf(A[6], c1.z, acc);
  acc = fmaf(A[7], c1.w, acc);
  return acc;
}

DEV float dot4(const float (&A)[4], float4 c0) {
  float acc = A[0] * c0.x;
  acc = fmaf(A[1], c0.y, acc);
  acc = fmaf(A[2], c0.z, acc);
  acc = fmaf(A[3], c0.w, acc);
  return acc;
}

// --- cross-lane reduction with distribution (corr kernel, unchanged) ------
DEV float reduce_dist_64(float (&cur)[64], int lane) {
#pragma unroll
  for (int d = 0; d < 6; ++d) {
    const int dist = 1 << d;
    const int up = (lane >> d) & 1;
#pragma unroll
    for (int m = 0; m < (64 >> (d + 1)); ++m) {
      float snd = up ? cur[2 * m]     : cur[2 * m + 1];
      float kp  = up ? cur[2 * m + 1] : cur[2 * m];
      float r = __shfl_xor(snd, dist, 64);
      cur[m] = kp + r;
    }
  }
  return cur[0];
}

DEV float reduce_dist_32(float (&cur)[32], int lane) {
#pragma unroll
  for (int d = 0; d < 5; ++d) {
    const int dist = 1 << d;
    const int up = (lane >> d) & 1;
#pragma unroll
    for (int m = 0; m < (32 >> (d + 1)); ++m) {
      float snd = up ? cur[2 * m]     : cur[2 * m + 1];
      float kp  = up ? cur[2 * m + 1] : cur[2 * m];
      float r = __shfl_xor(snd, dist, 64);
      cur[m] = kp + r;
    }
  }
  float v = cur[0];
  v += __shfl_xor(v, 32, 64);
  return v;
}

// --- Phase 1: correlation matrices (one wave per batch) — UNCHANGED -------
__global__ __launch_bounds__(64) void corr_kernel(
    const float* __restrict__ sites, float* __restrict__ cmat) {
  const int b = blockIdx.x;
  const int lane = threadIdx.x;
  const float4* base = reinterpret_cast<const float4*>(sites) + (size_t)b * 1024;

  float4 v[16];
#pragma unroll
  for (int s = 0; s < 16; ++s) v[s] = base[s * 64 + lane];

  float aw[64];
#pragma unroll
  for (int i = 0; i < 8; ++i) {
#pragma unroll
    for (int j = 0; j < 8; ++j) {
      float4 a = v[i], c = v[8 + j];
      aw[i * 8 + j] =
          fmaf(a.x, c.x, fmaf(a.y, c.y, fmaf(a.z, c.z, a.w * c.w)));
    }
  }
  float cw = reduce_dist_64(aw, lane);

  float alr[32];
#pragma unroll
  for (int i = 0; i < 4; ++i) {
#pragma unroll
    for (int j = 0; j < 4; ++j) {
      float4 a = v[i], c = v[4 + j];
      alr[i * 4 + j] =
          fmaf(a.x, c.x, fmaf(a.y, c.y, fmaf(a.z, c.z, a.w * c.w)));
      float4 a2 = v[8 + i], c2 = v[12 + j];
      alr[16 + i * 4 + j] =
          fmaf(a2.x, c2.x, fmaf(a2.y, c2.y, fmaf(a2.z, c2.z, a2.w * c2.w)));
    }
  }
  float clr = reduce_dist_32(alr, lane);

  float* row = cmat + (size_t)b * 96;
  row[lane] = cw;
  if (lane < 32) row[64 + lane] = clr;
}

// --- Phase 2: lane-parallel eigensolve -------------------------------------
// 4 lanes per batch, 16 batches per 64-thread block, 512 blocks = 512 waves
// (vs 128 before). Per-lane state ~60 VGPRs (vs ~150+): no spill risk.
__global__ __launch_bounds__(64) void phi_kernel(
    const float* __restrict__ cmat, float* __restrict__ out) {
  __shared__ float4 lds4[16 * 25];  // 16 batches x 96 floats, padded to 100
  const int t = threadIdx.x;
  const int b0 = blockIdx.x * 16;

  const float4* src = reinterpret_cast<const float4*>(cmat) + (size_t)b0 * 24;
#pragma unroll
  for (int r = 0; r < 6; ++r) {
    int q = r * 64 + t;            // 384 float4 total = 6 * 64
    float4 val = src[q];
    int bl = q / 24;
    int e4 = q - bl * 24;
    lds4[bl * 25 + e4] = val;
  }
  __syncthreads();

  const int u = t & 3;          // lane within 4-lane group
  const int grp = t >> 2;       // batch within block (0..15)
  const int gbase = t & ~3;
  const int base2 = t & ~1;
  const int w = u & 1;
  const float* Crow = reinterpret_cast<const float*>(lds4) + grp * 100;

  // ---- build W rows of M = Cw*Cw^T in position-slot order ----
  // round-0 layout: T=[0,1,2,3], B=[7,6,5,4]; col(slot s) = (s&1)? 7-(s>>1) : s>>1
  float Cp[8], Cq[8];
  {
    const float4* P = reinterpret_cast<const float4*>(Crow + u * 8);
    float4 a0 = P[0], a1 = P[1];
    Cp[0] = a0.x; Cp[1] = a0.y; Cp[2] = a0.z; Cp[3] = a0.w;
    Cp[4] = a1.x; Cp[5] = a1.y; Cp[6] = a1.z; Cp[7] = a1.w;
    const float4* Q = reinterpret_cast<const float4*>(Crow + (7 - u) * 8);
    float4 e0 = Q[0], e1 = Q[1];
    Cq[0] = e0.x; Cq[1] = e0.y; Cq[2] = e0.z; Cq[3] = e0.w;
    Cq[4] = e1.x; Cq[5] = e1.y; Cq[6] = e1.z; Cq[7] = e1.w;
  }
  float rT[8], rB[8];
#pragma unroll
  for (int sl = 0; sl < 8; ++sl) {
    const int j = (sl & 1) ? (7 - (sl >> 1)) : (sl >> 1);  // compile-time
    const float4* J = reinterpret_cast<const float4*>(Crow + j * 8);
    float4 c0 = J[0], c1 = J[1];   // broadcast across the 4-lane group: free
    rT[sl] = dot8(Cp, c0, c1);
    rB[sl] = dot8(Cq, c0, c1);
  }

  // ---- build L/R rows (L: lanes 0-1 at cmat[64..80), R: lanes 2-3 at [80..96)) ----
  const int cbase = 64 + ((u >> 1) << 4);
  float Dp[4], Dq[4];
  {
    float4 dp = *reinterpret_cast<const float4*>(Crow + cbase + w * 4);
    float4 dq = *reinterpret_cast<const float4*>(Crow + cbase + (3 - w) * 4);
    Dp[0] = dp.x; Dp[1] = dp.y; Dp[2] = dp.z; Dp[3] = dp.w;
    Dq[0] = dq.x; Dq[1] = dq.y; Dq[2] = dq.z; Dq[3] = dq.w;
  }
  float rT4[4], rB4[4];
#pragma unroll
  for (int sl = 0; sl < 4; ++sl) {
    const int j = (sl & 1) ? (3 - (sl >> 1)) : (sl >> 1);
    float4 cj = *reinterpret_cast<const float4*>(Crow + cbase + j * 4);
    rT4[sl] = dot4(Dp, cj);
    rB4[sl] = dot4(Dq, cj);
  }

  // ---- fused rounds: 21 W rounds (3 sweeps), 9 L/R rounds on even rounds ----
#pragma unroll
  for (int rr = 0; rr < 21; ++rr) {
    w_round(rT, rB, u, gbase);
    if ((rr & 1) == 0 && rr < 18) {   // rr = 0,2,...,16 -> 9 rounds = 3 sweeps
      h_round(rT4, rB4, w, base2);
      h_migrate(rT4, rB4, w);
    }
    w_migrate(rT, rB, u, gbase);
  }
  // after 21 = 3*7 migrations the layout is back to round-0 positions

  // ---- entropies ----
  const bool q0 = (u & 1) != 0, q1 = (u & 2) != 0;
  float eTa = q0 ? rT[2] : rT[0], eTb = q0 ? rT[6] : rT[4];
  float lT = q1 ? eTb : eTa;              // diag of row T_u (slot 2u)
  float eBa = q0 ? rB[3] : rB[1], eBb = q0 ? rB[7] : rB[5];
  float lB = q1 ? eBb : eBa;              // diag of row B_u (slot 2u+1)
  lT = fmaxf(lT, 0.0f) + 1e-10f;
  lB = fmaxf(lB, 0.0f) + 1e-10f;
  float sm = lT + lB;
  sm += __shfl_xor(sm, 1, 64);
  sm += __shfl_xor(sm, 2, 64);            // 4-lane group sum: all 8 eigenvalues
  float inv = 1.0f / sm;
  float pT = lT * inv, pB = lB * inv;
  float hh = fmaf(pT, __logf(pT + 1e-10f), pB * __logf(pB + 1e-10f));
  hh += __shfl_xor(hh, 1, 64);
  hh += __shfl_xor(hh, 2, 64);
  float Sw = -hh;

  float l0 = w ? rT4[2] : rT4[0];
  float l1 = w ? rB4[3] : rB4[1];
  l0 = fmaxf(l0, 0.0f) + 1e-10f;
  l1 = fmaxf(l1, 0.0f) + 1e-10f;
  float s4 = l0 + l1;
  s4 += __shfl_xor(s4, 1, 64);            // 2-lane sum: all 4 eigenvalues
  float i4 = 1.0f / s4;
  float p0 = l0 * i4, p1 = l1 * i4;
  float h4 = fmaf(p0, __logf(p0 + 1e-10f), p1 * __logf(p1 + 1e-10f));
  h4 += __shfl_xor(h4, 1, 64);
  float S4 = -h4;                         // lanes 0-1: Sl; lanes 2-3: Sr
  float So = __shfl_xor(S4, 2, 64);       // the other half's entropy
  float phi = fmaxf(Sw - S4 - So, 0.0f);  // same value on all 4 lanes
  if (u == 0) out[b0 + grp] = phi;
}

extern "C" void kernel_launch(void* const* d_in, const int* in_sizes, int n_in,
                              void* d_out, int out_size, void* d_ws, size_t ws_size,
                              hipStream_t stream) {
  const float* sites = (const float*)d_in[0];   // [8192, 16, 256] f32
  float* out = (float*)d_out;                   // [8192] f32
  float* cmat = (float*)d_ws;                   // 8192*96*4 = 3 MiB used

  corr_kernel<<<8192, 64, 0, stream>>>(sites, cmat);
  phi_kernel<<<512, 64, 0, stream>>>(cmat, out);
}